// Round 5
// baseline (4762.926 us; speedup 1.0000x reference)
//
#include <hip/hip_runtime.h>
#include <hip/hip_cooperative_groups.h>
#include <cmath>

typedef __bf16 bf16x8 __attribute__((ext_vector_type(8)));
typedef float floatx4 __attribute__((ext_vector_type(4)));
typedef unsigned ux4 __attribute__((ext_vector_type(4)));
typedef unsigned short u16;

#define B_ 16
#define T_ 512
#define D_ 512
#define H_ 1024
#define G_ 2048  // 2H
#define BH (B_ * H_)
#define HP 1058  // lds h row pitch in u16: 2116 B ≡ 68 mod 128 -> conflict-free rows

// ---------------- cast fp32 -> bf16 (RNE) ----------------
__global__ void cast_f32_bf16(const float* __restrict__ src, u16* __restrict__ dst, int n) {
  int i = blockIdx.x * blockDim.x + threadIdx.x;
  int stride = gridDim.x * blockDim.x;
  for (; i < n; i += stride) {
    __bf16 b = (__bf16)src[i];
    dst[i] = *reinterpret_cast<u16*>(&b);
  }
}

// ---------------- w = x @ W^T  (bf16 MFMA, fp32 out), layout w[t][b][2H] ----------------
__launch_bounds__(256, 1)
__global__ void gemm_xW(const u16* __restrict__ xb, const u16* __restrict__ Wb,
                        float* __restrict__ w) {
  const int lane = threadIdx.x & 63;
  const int wv = threadIdx.x >> 6;
  const int rt0 = blockIdx.x * 16;
  const int bidx = rt0 >> 9;
  const int t0 = rt0 & 511;
  const int am = lane & 15;
  const int kq = lane >> 4;

  bf16x8 af[16];
  {
    const u16* xrow = xb + (size_t)(rt0 + am) * D_ + kq * 8;
#pragma unroll
    for (int kk = 0; kk < 16; ++kk)
      af[kk] = *reinterpret_cast<const bf16x8*>(xrow + kk * 32);
  }

#pragma unroll 1
  for (int nt = 0; nt < 32; ++nt) {
    const int n0 = wv * 512 + nt * 16;
    floatx4 acc = {0.f, 0.f, 0.f, 0.f};
    const u16* wrow = Wb + (size_t)(n0 + am) * D_ + kq * 8;
#pragma unroll
    for (int kk = 0; kk < 16; ++kk) {
      bf16x8 bfr = *reinterpret_cast<const bf16x8*>(wrow + kk * 32);
      acc = __builtin_amdgcn_mfma_f32_16x16x32_bf16(af[kk], bfr, acc, 0, 0, 0);
    }
#pragma unroll
    for (int i = 0; i < 4; ++i) {
      int m = kq * 4 + i;
      w[(size_t)((t0 + m) * 16 + bidx) * G_ + n0 + am] = acc[i];
    }
  }
}

// ---------------- in-place LayerNorm over rows of 2048 ----------------
__launch_bounds__(256, 1)
__global__ void layernorm_rows(float* __restrict__ w, const float* __restrict__ gamma,
                               const float* __restrict__ beta) {
  float* r = w + (size_t)blockIdx.x * G_;
  float v[8];
  float s = 0.f, ss = 0.f;
#pragma unroll
  for (int i = 0; i < 8; ++i) {
    v[i] = r[threadIdx.x + i * 256];
    s += v[i];
    ss += v[i] * v[i];
  }
#pragma unroll
  for (int d = 1; d < 64; d <<= 1) {
    s += __shfl_xor(s, d, 64);
    ss += __shfl_xor(ss, d, 64);
  }
  __shared__ float ls[4], lss[4];
  const int wv = threadIdx.x >> 6;
  if ((threadIdx.x & 63) == 0) { ls[wv] = s; lss[wv] = ss; }
  __syncthreads();
  float S = ls[0] + ls[1] + ls[2] + ls[3];
  float SS = lss[0] + lss[1] + lss[2] + lss[3];
  float mu = S * (1.f / 2048.f);
  float var = SS * (1.f / 2048.f) - mu * mu;
  float rs = rsqrtf(var + 1e-5f);
#pragma unroll
  for (int i = 0; i < 8; ++i) {
    int g = threadIdx.x + i * 256;
    r[g] = (v[i] - mu) * rs * gamma[g] + beta[g];
  }
}

// ---------------- persistent LiGRU scan: 64 CUs, 4-group pipeline -----------------
// Diagnosis (R4): phase was LDS-throughput-bound (128 ds_read_b128/phase through one
// CU's LDS pipe + 672cy/phase bank conflicts), with V(publish->visible) ~1.5us as
// the co-equal term. Fixes:
//  * 64 blocks (16 h-cols each): per-CU A-reads halve to 64 b128/phase.
//  * HP=1058 (stride 2116B ≡ 68 mod 128): conflict-free row access; A reads only
//    the 4 LIVE rows of the current group (am&3 duplicate -> broadcast).
//  * G=4 batch groups, 4 phases/step: publish->consume slack = 3 phases >= V, so
//    tag polls pass on the in-flight bundle; retry (sc0sc1 batched) is the net.
//  * bundles + w issued at phase START for phase k+1 (full phase in flight).
//  * role split: waves 0-3 = compute/update/publish (never wait vmcnt);
//    waves 4-7 = pollers/stagers (never store). All transport sc0 sc1.
__launch_bounds__(512, 1)
__global__ void ligru_scan(const float* __restrict__ w, const u16* __restrict__ Ub,
                           const float* __restrict__ h0, float* __restrict__ out,
                           unsigned* __restrict__ hbuf) {
  const int tid = threadIdx.x;
  const int lane = tid & 63;
  const int wv = tid >> 6;
  const int am = lane & 15;
  const int kq = lane >> 4;
  const int blk = blockIdx.x;
  const int j0 = blk * 16;
  const bool loader = (tid >= 256);

  __shared__ u16 lds_h[16 * HP];         // row b = batch b's h (bf16 bits)
  __shared__ float lds_r[2][2][16][16];  // [tile a/z][K-half][m-row][n-col]
  __shared__ float lds_w[2][4][2][16];   // [phase parity][batch-loc][gate][col]

  const int jt = wv & 1;         // 0: a-gates, 1: z-gates (waves 0-3)
  const int kh = (wv >> 1) & 1;  // K half (waves 0-3)

  // U fragments (compute waves only): 16 gate-rows x K=512 half
  bf16x8 uf[16];
  if (!loader) {
    const int grow = jt * H_ + j0 + am;
    const u16* urow = Ub + (size_t)grow * H_ + kh * 512 + kq * 8;
#pragma unroll
    for (int kk = 0; kk < 16; ++kk)
      uf[kk] = *reinterpret_cast<const bf16x8*>(urow + kk * 32);
  }

  // updater ownership (tid<256): batch ub, col cl; wave g updates at phase g
  const int ub = tid >> 4;
  const int cl = tid & 15;
  const int col = j0 + cl;
  float hreg = 0.f;

  // loader mapping (tid>=256)
  const int li = tid & 255;
  const int wb = (li >> 5) & 3;   // w batch-local
  const int wg = (li >> 4) & 1;   // w gate
  const int wc = li & 15;         // w col
  ux4 chv0, chv1, chv2, chv3;
  float wnx = 0.f;

#define ISSUE_B(cb)                                                            \
  asm volatile("global_load_dwordx4 %0, %4, off sc0 sc1\n\t"                   \
               "global_load_dwordx4 %1, %5, off sc0 sc1\n\t"                   \
               "global_load_dwordx4 %2, %6, off sc0 sc1\n\t"                   \
               "global_load_dwordx4 %3, %7, off sc0 sc1"                       \
               : "=&v"(chv0), "=&v"(chv1), "=&v"(chv2), "=&v"(chv3)            \
               : "v"(cb), "v"((cb) + H_), "v"((cb) + 2 * H_), "v"((cb) + 3 * H_) \
               : "memory")

#define TAGCHK(tg)                                                             \
  ((((chv0.x ^ (tg)) | (chv0.y ^ (tg)) | (chv0.z ^ (tg)) | (chv0.w ^ (tg)) |   \
     (chv1.x ^ (tg)) | (chv1.y ^ (tg)) | (chv1.z ^ (tg)) | (chv1.w ^ (tg)) |   \
     (chv2.x ^ (tg)) | (chv2.y ^ (tg)) | (chv2.z ^ (tg)) | (chv2.w ^ (tg)) |   \
     (chv3.x ^ (tg)) | (chv3.y ^ (tg)) | (chv3.z ^ (tg)) | (chv3.w ^ (tg))) &  \
    0xFFFFu))

  // ---- init ----
  if (!loader) {
    hreg = h0[col];
    __bf16 hb = (__bf16)hreg;
    unsigned pk = ((unsigned)*reinterpret_cast<u16*>(&hb) << 16) | 1u;
    unsigned* pp = hbuf + ub * H_ + col;
    asm volatile("global_store_dword %0, %1, off sc0 sc1"
                 :: "v"(pp), "v"(pk) : "memory");
  } else {
    if (li < 128) {
      const float* ws = w + (size_t)wb * G_ + wg * H_ + j0 + wc;
      asm volatile("global_load_dword %0, %1, off nt"
                   : "=&v"(wnx) : "v"(ws) : "memory");
    }
    const unsigned* nb = hbuf + 4 * li;  // parity 0, group 0
    ISSUE_B(nb);
  }

#pragma unroll 1
  for (int t = 0; t < T_; ++t) {
#pragma unroll 1
    for (int g = 0; g < 4; ++g) {
      const unsigned tag = (unsigned)(t + 1);
      if (loader) {
        // ---- wait for in-flight bundle + w; tag check; batched retry net ----
        asm volatile("s_waitcnt vmcnt(0)"
                     : "+v"(chv0), "+v"(chv1), "+v"(chv2), "+v"(chv3), "+v"(wnx)
                     :: "memory");
        __builtin_amdgcn_sched_barrier(0);
        unsigned bad = TAGCHK(tag);
        if (bad) {
          const unsigned* cb = hbuf + (size_t)(t & 1) * BH + 4 * g * H_ + 4 * li;
          unsigned rounds = 0;
          do {
            ISSUE_B(cb);
            asm volatile("s_waitcnt vmcnt(0)"
                         : "+v"(chv0), "+v"(chv1), "+v"(chv2), "+v"(chv3)
                         :: "memory");
            bad = TAGCHK(tag);
          } while (bad && ++rounds < 4096u);
        }
        // ---- stage w for THIS phase's update ----
        if (li < 128) lds_w[g & 1][wb][wg][wc] = wnx;
        // ---- unpack 4 chunks -> lds_h rows 4g..4g+3 ----
        {
          unsigned lo, hi; uint2 pk2;
          lo = (chv0.x >> 16) | (chv0.y & 0xFFFF0000u);
          hi = (chv0.z >> 16) | (chv0.w & 0xFFFF0000u);
          pk2.x = lo; pk2.y = hi;
          *reinterpret_cast<uint2*>(&lds_h[(4 * g + 0) * HP + 4 * li]) = pk2;
          lo = (chv1.x >> 16) | (chv1.y & 0xFFFF0000u);
          hi = (chv1.z >> 16) | (chv1.w & 0xFFFF0000u);
          pk2.x = lo; pk2.y = hi;
          *reinterpret_cast<uint2*>(&lds_h[(4 * g + 1) * HP + 4 * li]) = pk2;
          lo = (chv2.x >> 16) | (chv2.y & 0xFFFF0000u);
          hi = (chv2.z >> 16) | (chv2.w & 0xFFFF0000u);
          pk2.x = lo; pk2.y = hi;
          *reinterpret_cast<uint2*>(&lds_h[(4 * g + 2) * HP + 4 * li]) = pk2;
          lo = (chv3.x >> 16) | (chv3.y & 0xFFFF0000u);
          hi = (chv3.z >> 16) | (chv3.w & 0xFFFF0000u);
          pk2.x = lo; pk2.y = hi;
          *reinterpret_cast<uint2*>(&lds_h[(4 * g + 3) * HP + 4 * li]) = pk2;
        }
        // ---- issue NEXT phase's bundle + w (full phase in flight; data
        //      published >= 3 phases ago) ----
        {
          const int gn = (g + 1) & 3;
          const int tb = (g == 3) ? (t + 1) : t;
          const int tw = (g == 3) ? ((t + 1 < T_) ? t + 1 : t) : t;
          if (li < 128) {
            const float* ws = w + (size_t)(tw * 16 + 4 * gn + wb) * G_ +
                              wg * H_ + j0 + wc;
            asm volatile("global_load_dword %0, %1, off nt"
                         : "=&v"(wnx) : "v"(ws) : "memory");
          }
          const unsigned* nb = hbuf + (size_t)(tb & 1) * BH + 4 * gn * H_ + 4 * li;
          ISSUE_B(nb);
        }
        asm volatile("s_waitcnt lgkmcnt(0)" ::: "memory");
      }
      __builtin_amdgcn_s_barrier();  // (A) staging complete
      __builtin_amdgcn_sched_barrier(0);

      if (!loader) {
        // ---- gates: A = 4 live h rows (dup x4 across am), B = uf ----
        const u16* hb = &lds_h[(4 * g + (am & 3)) * HP + kh * 512 + kq * 8];
        floatx4 aa[4];
        aa[0] = aa[1] = aa[2] = aa[3] = floatx4{0.f, 0.f, 0.f, 0.f};
#pragma unroll
        for (int kk = 0; kk < 16; ++kk) {
          bf16x8 x = *reinterpret_cast<const bf16x8*>(hb + kk * 32);
          aa[kk & 3] = __builtin_amdgcn_mfma_f32_16x16x32_bf16(x, uf[kk], aa[kk & 3], 0, 0, 0);
        }
        floatx4 acc = (aa[0] + aa[1]) + (aa[2] + aa[3]);
#pragma unroll
        for (int i = 0; i < 4; ++i)
          lds_r[jt][kh][kq * 4 + i][am] = acc[i];
        asm volatile("s_waitcnt lgkmcnt(0)" ::: "memory");
      }
      __builtin_amdgcn_s_barrier();  // (B) partials complete
      __builtin_amdgcn_sched_barrier(0);

      // ---- update: wave g (threads owning batches 4g..4g+3) ----
      if (!loader && wv == g) {
        const int q = ub & 3;
        float a = lds_r[0][0][q][cl] + lds_r[0][1][q][cl] + lds_w[g & 1][q][0][cl];
        float z = lds_r[1][0][q][cl] + lds_r[1][1][q][cl] + lds_w[g & 1][q][1][cl];
        float zs = 1.f / (1.f + __expf(-z));
        float hn = zs * hreg + (1.f - zs) * fmaxf(a, 0.f);
        hreg = hn;
        __bf16 hb16 = (__bf16)hn;
        unsigned pk = ((unsigned)*reinterpret_cast<u16*>(&hb16) << 16) |
                      (unsigned)(t + 2);
        unsigned* pp = hbuf + (size_t)((t + 1) & 1) * BH + ub * H_ + col;
        asm volatile("global_store_dword %0, %1, off sc0 sc1"
                     :: "v"(pp), "v"(pk) : "memory");
        __builtin_nontemporal_store(hn, &out[((size_t)ub * T_ + t) * H_ + col]);
      }
    }
  }
#undef ISSUE_B
#undef TAGCHK
}

// ---------------- host ----------------
extern "C" void kernel_launch(void* const* d_in, const int* in_sizes, int n_in,
                              void* d_out, int out_size, void* d_ws, size_t ws_size,
                              hipStream_t stream) {
  (void)in_sizes; (void)n_in; (void)out_size; (void)ws_size;
  const float* x = (const float*)d_in[0];
  const float* Ww = (const float*)d_in[1];
  const float* Uw = (const float*)d_in[2];
  const float* gamma = (const float*)d_in[3];
  const float* beta = (const float*)d_in[4];
  const float* h0 = (const float*)d_in[5];
  float* out = (float*)d_out;

  char* p = (char*)d_ws;
  u16* xb = (u16*)p;      p += (size_t)8192 * 512 * 2;   // 8 MB
  u16* Wb = (u16*)p;      p += (size_t)2048 * 512 * 2;   // 2 MB
  u16* Ub = (u16*)p;      p += (size_t)2048 * 1024 * 2;  // 4 MB
  float* w = (float*)p;   p += (size_t)8192 * 2048 * 4;  // 64 MB  [T][B][G]
  unsigned* hbuf = (unsigned*)p; p += (size_t)2 * BH * 4; // 128 KB tagged dwords

  hipMemsetAsync(hbuf, 0, (size_t)2 * BH * 4, stream);  // tag 0 != any real tag
  cast_f32_bf16<<<512, 256, 0, stream>>>(x, xb, 8192 * 512);
  cast_f32_bf16<<<256, 256, 0, stream>>>(Ww, Wb, 2048 * 512);
  cast_f32_bf16<<<256, 256, 0, stream>>>(Uw, Ub, 2048 * 1024);
  gemm_xW<<<512, 256, 0, stream>>>(xb, Wb, w);
  layernorm_rows<<<8192, 256, 0, stream>>>(w, gamma, beta);

  const float* wc = w;
  const u16* Ubc = Ub;
  void* args[5] = { (void*)&wc, (void*)&Ubc, (void*)&h0, (void*)&out, (void*)&hbuf };
  hipLaunchCooperativeKernel((void*)ligru_scan, dim3(64), dim3(512), args, 0, stream);
}